// Round 16
// baseline (154.258 us; speedup 1.0000x reference)
//
#include <hip/hip_runtime.h>
#include <math.h>

#define B_  16
#define C_  256
#define N_  2048
#define CQ_ 64

typedef __attribute__((ext_vector_type(8))) short bf16x8;
typedef __attribute__((ext_vector_type(8))) unsigned short u16x8;
typedef __attribute__((ext_vector_type(16))) float f32x16;

#define kLOG2E 1.4426950408889634f

__device__ __forceinline__ unsigned short f2bf(float f) {
  union { float f; unsigned u; } v; v.f = f;
  unsigned r = v.u + 0x7FFFu + ((v.u >> 16) & 1u);
  return (unsigned short)(r >> 16);
}

__device__ __forceinline__ void gload16(const void* g, void* l) {
  __builtin_amdgcn_global_load_lds(
      (const __attribute__((address_space(1))) void*)g,
      (__attribute__((address_space(3))) void*)l, 16, 0, 0);
}

__device__ __forceinline__ f32x16 zero16() {
  f32x16 z;
  #pragma unroll
  for (int i = 0; i < 16; ++i) z[i] = 0.f;
  return z;
}

// v_cvt_pk_bf16_f32: pack two f32 -> u32 (lo = a, hi = b), RNE
__device__ __forceinline__ unsigned cvtpk(float a, float b) {
  unsigned r;
  asm("v_cvt_pk_bf16_f32 %0, %1, %2" : "=v"(r) : "v"(a), "v"(b));
  return r;
}
// v_permlane32_swap_b32: a.lanes[32:63] <-> b.lanes[0:31]
__device__ __forceinline__ void pswap(unsigned& a, unsigned& b) {
  asm("v_permlane32_swap_b32 %0, %1" : "+v"(a), "+v"(b));
}

// fragment read from a [rows][64] bf16 LDS tile with 16B-chunk XOR swizzle
__device__ __forceinline__ bf16x8 frag_ld(const unsigned short* base, int row, int kb, int hi) {
  const int byteoff = row * 128 + ((((kb << 1) + hi) ^ (row & 7)) << 4);
  return *(const bf16x8*)((const char*)base + byteoff);
}

// Fragment-ordered global layouts (consumed register-direct, coalesced):
//  f_f/g_f: [b][tile64(32)][slot(8)][row(64)][8 bf16]   (slot = k-chunk of c)
//  h_f:     [b][tile64(32)][slot(8)][c-row(256)][8 bf16] (slot = k-chunk of n)

// ---------------- Kernel 0a: pack weights -> bf16 swizzled Wall[384][256] ----
__global__ __launch_bounds__(256) void pack_kernel(
    const float* __restrict__ Wf, const float* __restrict__ bf,
    const float* __restrict__ Wg, const float* __restrict__ bg,
    const float* __restrict__ Wh, const float* __restrict__ bh,
    unsigned short* __restrict__ Wall, float* __restrict__ ball)
{
    const int t = threadIdx.x;
    const int o = blockIdx.x * 64 + (t >> 2);
    const int cq = (t & 3) * 64;
    const float* W; const float* bias; int r;
    if (o < 64)       { W = Wf; bias = bf; r = o; }
    else if (o < 128) { W = Wg; bias = bg; r = o - 64; }
    else              { W = Wh; bias = bh; r = o - 128; }
    for (int j = 0; j < 64; ++j) {
        const int c = cq + j;
        const int chunk = ((c >> 3) & 7) ^ (o & 7);
        Wall[(size_t)o * 256 + (c & ~63) + chunk * 8 + (c & 7)] = f2bf(W[(size_t)r * 256 + c]);
    }
    if ((t & 3) == 0) ball[o] = bias[r];
}

// ---------------- Kernel 1: projections via MFMA, fused x-transpose ----------
__global__ __launch_bounds__(256) void projmm_kernel(
    const unsigned short* __restrict__ Wall, const float* __restrict__ ball,
    const float* __restrict__ x,
    unsigned short* __restrict__ f_f, unsigned short* __restrict__ g_f,
    unsigned short* __restrict__ h_f)
{
    const int L = blockIdx.x;
    const int slot = L >> 3;
    const int b  = (L & 7) + (slot >= 48 ? 8 : 0);
    const int id2 = (slot >= 48) ? slot - 48 : slot;
    const int ot = id2 % 3, nt = id2 / 3;

    __shared__ __align__(16) unsigned short Sbuf[2][2][128 * 64];
    __shared__ float biasS[128];

    const int t = threadIdx.x, w = t >> 6, lane = t & 63, hi = lane >> 5, ln = lane & 31;
    const int oh = w & 1, nh = w >> 1;

    if (t < 128) biasS[t] = ball[ot * 128 + t];

    auto STAGE = [&](int k, int buf) {
        #pragma unroll
        for (int p = 0; p < 4; ++p) {
            const int q = p * 256 + t, r = q >> 3, cc = q & 7;
            gload16((const char*)Wall + ((size_t)(ot*128 + r) * 256 + k*64 + cc*8) * 2,
                    (char*)&Sbuf[buf][0][0] + q * 16);
        }
        const int row = t & 127;
        const int thi = t >> 7;
        const float* xsrc = x + ((size_t)b * C_ + k*64) * N_ + nt*128 + row;
        unsigned short* Xd = &Sbuf[buf][1][0];
        #pragma unroll
        for (int p = 0; p < 4; ++p) {
            const int k8 = p*2 + thi;
            u16x8 v;
            #pragma unroll
            for (int j = 0; j < 8; ++j)
                v[j] = f2bf(xsrc[(size_t)(k8*8 + j) * N_]);
            *(u16x8*)&Xd[(row * 8 + (k8 ^ (row & 7))) * 8] = v;
        }
    };

    f32x16 a00 = zero16(), a01 = zero16(), a10 = zero16(), a11 = zero16();

    STAGE(0, 0);
    for (int k = 0; k < 4; ++k) {
        __syncthreads();
        if (k < 3) STAGE(k + 1, (k + 1) & 1);
        const unsigned short* Wl = &Sbuf[k & 1][0][0];
        const unsigned short* Xl = &Sbuf[k & 1][1][0];
        #pragma unroll
        for (int kb = 0; kb < 4; ++kb) {
            bf16x8 w0 = frag_ld(Wl, oh*64 + ln,      kb, hi);
            bf16x8 w1 = frag_ld(Wl, oh*64 + 32 + ln, kb, hi);
            bf16x8 x0 = frag_ld(Xl, nh*64 + ln,      kb, hi);
            bf16x8 x1 = frag_ld(Xl, nh*64 + 32 + ln, kb, hi);
            a00 = __builtin_amdgcn_mfma_f32_32x32x16_bf16(w0, x0, a00, 0, 0, 0);
            a01 = __builtin_amdgcn_mfma_f32_32x32x16_bf16(w0, x1, a01, 0, 0, 0);
            a10 = __builtin_amdgcn_mfma_f32_32x32x16_bf16(w1, x0, a10, 0, 0, 0);
            a11 = __builtin_amdgcn_mfma_f32_32x32x16_bf16(w1, x1, a11, 0, 0, 0);
        }
    }

    if (ot == 0) {
        unsigned short* y = (oh == 0) ? f_f : g_f;
        const int tile64 = nt*2 + nh;
        #pragma unroll
        for (int j = 0; j < 2; ++j) {
            const int row = j*32 + ln;
            #pragma unroll
            for (int i = 0; i < 2; ++i) {
                const f32x16& a = (i == 0) ? (j == 0 ? a00 : a01)
                                           : (j == 0 ? a10 : a11);
                float v[16];
                #pragma unroll
                for (int r = 0; r < 16; ++r) {
                    const int cl = i*32 + (r & 3) + ((r >> 2) << 3) + 4*hi;
                    v[r] = fmaxf(a[r] + biasS[oh*64 + cl], 0.f);
                }
                #pragma unroll
                for (int kpa = 0; kpa < 2; ++kpa) {
                    unsigned u00 = cvtpk(v[8*kpa+0], v[8*kpa+1]);
                    unsigned u10 = cvtpk(v[8*kpa+2], v[8*kpa+3]);
                    unsigned u01 = cvtpk(v[8*kpa+4], v[8*kpa+5]);
                    unsigned u11 = cvtpk(v[8*kpa+6], v[8*kpa+7]);
                    pswap(u00, u01);
                    pswap(u10, u11);
                    union { unsigned u[4]; u16x8 w8; } pk;
                    pk.u[0] = u00; pk.u[1] = u10; pk.u[2] = u01; pk.u[3] = u11;
                    const int ch = i*4 + kpa*2 + hi;
                    *(u16x8*)&y[((((size_t)b*32 + tile64)*8 + ch)*64 + row) * 8] = pk.w8;
                }
            }
        }
    } else {
        __syncthreads();
        unsigned short* Ht = &Sbuf[0][0][0];   // 128 x 128 bf16 = 32KB
        #pragma unroll
        for (int j = 0; j < 2; ++j) {
            const int n_lo = nh*64 + j*32 + ln;
            const int chunk = n_lo >> 3;
            #pragma unroll
            for (int i = 0; i < 2; ++i) {
                const f32x16& a = (i == 0) ? (j == 0 ? a00 : a01)
                                           : (j == 0 ? a10 : a11);
                #pragma unroll
                for (int r = 0; r < 16; ++r) {
                    const int o_lo = oh*64 + i*32 + (r & 3) + ((r >> 2) << 3) + 4*hi;
                    const int chs = (chunk & 8) | ((chunk ^ o_lo) & 7);
                    Ht[o_lo * 128 + chs * 8 + (n_lo & 7)] =
                        f2bf(fmaxf(a[r] + biasS[o_lo], 0.f));
                }
            }
        }
        __syncthreads();
        const int o_l = t & 127, half = t >> 7;
        const int c = (ot - 1) * 128 + o_l;
        const size_t tbase = ((size_t)b*32 + nt*2 + half) * 8;
        #pragma unroll
        for (int c8 = 0; c8 < 8; ++c8) {
            const int chunk = half*8 + c8;
            const int chs = (chunk & 8) | ((chunk ^ o_l) & 7);
            *(u16x8*)&h_f[((tbase + c8)*256 + c) * 8] =
                *(const u16x8*)&Ht[o_l * 128 + chs * 8];
        }
    }
}

// ---------------- Kernel 2: row stats — coalesced frag-direct loads ----------
__global__ __launch_bounds__(256) void stats_kernel(
    const unsigned short* __restrict__ f_f, const unsigned short* __restrict__ g_f,
    float* __restrict__ LL2)
{
    const int L = blockIdx.x;
    const int slot = L >> 3;
    const int b  = (L & 7) + (slot >= 32 ? 8 : 0);
    const int nb64 = (slot >= 32) ? slot - 32 : slot;

    __shared__ float pM[2][64];
    __shared__ float pZ[2][64];

    const int t = threadIdx.x;
    const int w = t >> 6, lane = t & 63, hi = lane >> 5, ln = lane & 31;
    const int mb = w >> 1, nb2 = w & 1;

    bf16x8 gf[4];
    #pragma unroll
    for (int kc = 0; kc < 4; ++kc)
        gf[kc] = *(const bf16x8*)&g_f[((((size_t)b*32 + nb64)*8 + kc*2+hi)*64 + nb2*32+ln) * 8];

    auto loadF = [&](int s, bf16x8 (&F)[4]) {
        #pragma unroll
        for (int kc = 0; kc < 4; ++kc)
            F[kc] = *(const bf16x8*)&f_f[((((size_t)b*32 + s)*8 + kc*2+hi)*64 + mb*32+ln) * 8];
    };

    float runM = -1e30f, runZ = 0.f;
    constexpr int NS = N_ / 64;

    bf16x8 Fa[4], Fb[4];
    loadF(0, Fa);

    auto step = [&](int s, bf16x8 (&Fc)[4], bf16x8 (&Fn)[4]) {
        const int sn = (s + 1 < NS) ? s + 1 : NS - 1;
        loadF(sn, Fn);
        f32x16 sacc = zero16();
        #pragma unroll
        for (int kc = 0; kc < 4; ++kc)
            sacc = __builtin_amdgcn_mfma_f32_32x32x16_bf16(Fc[kc], gf[kc], sacc, 0, 0, 0);
        float lm = sacc[0];
        #pragma unroll
        for (int r = 1; r < 16; ++r) lm = fmaxf(lm, sacc[r]);
        const float nm = fmaxf(runM, lm);
        float ssum = 0.f;
        #pragma unroll
        for (int r = 0; r < 16; ++r) ssum += __expf(sacc[r] - nm);
        runZ = runZ * __expf(runM - nm) + ssum;
        runM = nm;
    };

    for (int s2 = 0; s2 < NS / 2; ++s2) {
        step(2 * s2,     Fa, Fb);
        step(2 * s2 + 1, Fb, Fa);
    }

    {
        const float oM = __shfl_xor(runM, 32);
        const float oZ = __shfl_xor(runZ, 32);
        const float Mf = fmaxf(runM, oM);
        const float Zf = runZ * __expf(runM - Mf) + oZ * __expf(oM - Mf);
        if (lane < 32) { pM[mb][nb2 * 32 + lane] = Mf; pZ[mb][nb2 * 32 + lane] = Zf; }
    }
    __syncthreads();
    if (t < 64) {
        const float m0 = pM[0][t], m1 = pM[1][t];
        const float M  = fmaxf(m0, m1);
        const float Z  = pZ[0][t] * __expf(m0 - M) + pZ[1][t] * __expf(m1 - M);
        LL2[(size_t)b * N_ + nb64 * 64 + t] = fmaf(M, kLOG2E, log2f(Z));
    }
}

// ---------------- Kernel 3: fused output — barrier-free, in-register P ------
// 4 waves/block, each fully independent: wave (msub=w&1: 32m, chalf=w>>1: 128c)
// computes S(32m x 64n) swapped, exp+pack to pf[4] B-frags IN REGISTERS (r5-
// verified path), PV(128c x 32m) from coalesced h_f frags. No LDS, no barriers.
// S/exp 2x redundant chip-wide (c-halves) — trades cheap MFMA/VALU for zero
// synchronization. LL2 read wave-uniform from L2.
__global__ __launch_bounds__(256, 2) void out_kernel(
    const float* __restrict__ x,
    const unsigned short* __restrict__ f_f, const unsigned short* __restrict__ g_f,
    const unsigned short* __restrict__ h_f,
    const float* __restrict__ LL2,
    const float* __restrict__ gamma_p, float* __restrict__ out)
{
    const int L = blockIdx.x;                      // 512 blocks
    const int slot = L >> 3;                       // 0..63
    const int b = (L & 7) + (slot >= 32 ? 8 : 0);
    const int mb64 = (slot >= 32) ? slot - 32 : slot;
    const int mbase = mb64 * 64;

    const int t = threadIdx.x;
    const int w = t >> 6, lane = t & 63, hi = lane >> 5, ln = lane & 31;
    const int msub = w & 1, chalf = w >> 1;
    constexpr int NT = N_ / 64;

    const float* LLb = LL2 + (size_t)b * N_;

    // f frags (B-operand of swapped S): rows m = mbase + msub*32 + ln
    bf16x8 ff[4];
    #pragma unroll
    for (int kc = 0; kc < 4; ++kc)
        ff[kc] = *(const bf16x8*)&f_f[((((size_t)b*32 + mb64)*8 + kc*2+hi)*64 + msub*32+ln) * 8];

    // G frags for BOTH n-halves of a 64n tile: G[nh2*4+kc]
    auto LOAD_G = [&](int tt, bf16x8 (&G)[8]) {
        #pragma unroll
        for (int nh2 = 0; nh2 < 2; ++nh2)
            #pragma unroll
            for (int kc = 0; kc < 4; ++kc)
                G[nh2*4+kc] = *(const bf16x8*)&g_f[((((size_t)b*32 + tt)*8 + kc*2+hi)*64 +
                                                    nh2*32 + ln) * 8];
    };
    // H frags for one 32c chunk of this wave's 128c half
    auto LOAD_H = [&](int tt, int chunk, bf16x8 (&H)[4]) {
        #pragma unroll
        for (int kn = 0; kn < 4; ++kn)
            H[kn] = *(const bf16x8*)&h_f[((((size_t)b*32 + tt)*8 + kn*2+hi)*256 +
                                          chalf*128 + chunk*32 + ln) * 8];
    };

    // exp + pack one sacc (n-half nh2 of tile tt) -> pf[nh2*2], pf[nh2*2+1]
    auto PACK = [&](f32x16& s, int tt, int nh2, bf16x8 (&pf)[4]) {
        float4 llv[4];
        #pragma unroll
        for (int q = 0; q < 4; ++q)
            llv[q] = *(const float4*)&LLb[tt*64 + nh2*32 + q*8 + hi*4];
        #pragma unroll
        for (int r = 0; r < 16; ++r) {
            const float ll = ((const float*)&llv[r >> 2])[r & 3];
            s[r] = exp2f(fmaf(s[r], kLOG2E, -ll));
        }
        #pragma unroll
        for (int kpa = 0; kpa < 2; ++kpa) {
            unsigned u00 = cvtpk(s[8*kpa+0], s[8*kpa+1]);
            unsigned u10 = cvtpk(s[8*kpa+2], s[8*kpa+3]);
            unsigned u01 = cvtpk(s[8*kpa+4], s[8*kpa+5]);
            unsigned u11 = cvtpk(s[8*kpa+6], s[8*kpa+7]);
            pswap(u00, u01);
            pswap(u10, u11);
            union { unsigned u[4]; bf16x8 v; } pk;
            pk.u[0] = u00; pk.u[1] = u10; pk.u[2] = u01; pk.u[3] = u11;
            pf[nh2*2 + kpa] = pk.v;
        }
    };

    f32x16 acc0 = zero16(), acc1 = zero16(), acc2 = zero16(), acc3 = zero16();

    bf16x8 GA[8], GB[8];
    LOAD_G(0, GA);
    LOAD_G(1, GB);

    auto body = [&](int tt, bf16x8 (&Gc)[8]) {
        bf16x8 Ha[4], Hb[4];
        LOAD_H(tt, 0, Ha);                 // issue early; arrives during S/exp

        // S(tt): two n-halves, lanes = m, regs = n
        f32x16 s0 = zero16(), s1 = zero16();
        #pragma unroll
        for (int kc = 0; kc < 4; ++kc)
            s0 = __builtin_amdgcn_mfma_f32_32x32x16_bf16(Gc[kc],   ff[kc], s0, 0, 0, 0);
        #pragma unroll
        for (int kc = 0; kc < 4; ++kc)
            s1 = __builtin_amdgcn_mfma_f32_32x32x16_bf16(Gc[4+kc], ff[kc], s1, 0, 0, 0);

        if (tt + 2 < NT) LOAD_G(tt + 2, Gc);   // Gc free after S issues

        bf16x8 pf[4];
        PACK(s0, tt, 0, pf);
        PACK(s1, tt, 1, pf);

        LOAD_H(tt, 1, Hb);
        __builtin_amdgcn_s_setprio(1);
        #pragma unroll
        for (int kn = 0; kn < 4; ++kn)
            acc0 = __builtin_amdgcn_mfma_f32_32x32x16_bf16(Ha[kn], pf[kn], acc0, 0, 0, 0);
        __builtin_amdgcn_s_setprio(0);
        LOAD_H(tt, 2, Ha);
        __builtin_amdgcn_s_setprio(1);
        #pragma unroll
        for (int kn = 0; kn < 4; ++kn)
            acc1 = __builtin_amdgcn_mfma_f32_32x32x16_bf16(Hb[kn], pf[kn], acc1, 0, 0, 0);
        __builtin_amdgcn_s_setprio(0);
        LOAD_H(tt, 3, Hb);
        __builtin_amdgcn_s_setprio(1);
        #pragma unroll
        for (int kn = 0; kn < 4; ++kn)
            acc2 = __builtin_amdgcn_mfma_f32_32x32x16_bf16(Ha[kn], pf[kn], acc2, 0, 0, 0);
        #pragma unroll
        for (int kn = 0; kn < 4; ++kn)
            acc3 = __builtin_amdgcn_mfma_f32_32x32x16_bf16(Hb[kn], pf[kn], acc3, 0, 0, 0);
        __builtin_amdgcn_s_setprio(0);
    };

    for (int t2 = 0; t2 < NT / 2; ++t2) {
        body(2 * t2,     GA);
        body(2 * t2 + 1, GB);
    }

    // ---- epilogue: out = gamma*o + x   (per wave: 128c x 32m)
    const float gamma = gamma_p[0];
    #pragma unroll
    for (int chunk = 0; chunk < 4; ++chunk) {
        const f32x16& a = (chunk == 0) ? acc0 : (chunk == 1) ? acc1
                        : (chunk == 2) ? acc2 : acc3;
        #pragma unroll
        for (int r = 0; r < 16; ++r) {
            const int c = chalf*128 + chunk*32 + (r & 3) + ((r >> 2) << 3) + (hi << 2);
            const int m = mbase + msub * 32 + ln;
            const size_t idx = ((size_t)b * C_ + c) * N_ + m;
            out[idx] = fmaf(gamma, a[r], x[idx]);
        }
    }
}

extern "C" void kernel_launch(void* const* d_in, const int* in_sizes, int n_in,
                              void* d_out, int out_size, void* d_ws, size_t ws_size,
                              hipStream_t stream)
{
    (void)in_sizes; (void)n_in; (void)out_size; (void)ws_size;
    const float* x     = (const float*)d_in[0];
    const float* Wf    = (const float*)d_in[1];
    const float* bf    = (const float*)d_in[2];
    const float* Wg    = (const float*)d_in[3];
    const float* bg    = (const float*)d_in[4];
    const float* Wh    = (const float*)d_in[5];
    const float* bh    = (const float*)d_in[6];
    const float* gamma = (const float*)d_in[7];
    float* out = (float*)d_out;

    unsigned short* f_f  = (unsigned short*)d_ws;                 // [B][32][8][64][8] bf16
    unsigned short* g_f  = f_f + (size_t)B_ * N_ * CQ_;           // [B][32][8][64][8] bf16
    unsigned short* h_f  = g_f + (size_t)B_ * N_ * CQ_;           // [B][32][8][256][8] bf16
    float* LL2_ws = (float*)(h_f + (size_t)B_ * C_ * N_);         // [B][N]
    unsigned short* Wall = (unsigned short*)(LL2_ws + (size_t)B_ * N_); // [384][256] bf16 swz
    float* ball  = (float*)(Wall + (size_t)384 * 256);            // [384]

    pack_kernel<<<dim3(6), 256, 0, stream>>>(Wf, bf, Wg, bg, Wh, bh, Wall, ball);
    projmm_kernel<<<dim3(768), 256, 0, stream>>>(Wall, ball, x, f_f, g_f, h_f);
    stats_kernel<<<dim3(512), 256, 0, stream>>>(f_f, g_f, LL2_ws);
    out_kernel<<<dim3(512), 256, 0, stream>>>(x, f_f, g_f, h_f, LL2_ws, gamma, out);
}

// Round 17
// 106.645 us; speedup vs baseline: 1.4465x; 1.4465x over previous
//
#include <hip/hip_runtime.h>
#include <math.h>

#define B_  16
#define C_  256
#define N_  2048
#define CQ_ 64

typedef __attribute__((ext_vector_type(8))) short bf16x8;
typedef __attribute__((ext_vector_type(8))) unsigned short u16x8;
typedef __attribute__((ext_vector_type(16))) float f32x16;

#define kLOG2E 1.4426950408889634f

__device__ __forceinline__ unsigned short f2bf(float f) {
  union { float f; unsigned u; } v; v.f = f;
  unsigned r = v.u + 0x7FFFu + ((v.u >> 16) & 1u);
  return (unsigned short)(r >> 16);
}

__device__ __forceinline__ void gload16(const void* g, void* l) {
  __builtin_amdgcn_global_load_lds(
      (const __attribute__((address_space(1))) void*)g,
      (__attribute__((address_space(3))) void*)l, 16, 0, 0);
}

__device__ __forceinline__ f32x16 zero16() {
  f32x16 z;
  #pragma unroll
  for (int i = 0; i < 16; ++i) z[i] = 0.f;
  return z;
}

// v_cvt_pk_bf16_f32: pack two f32 -> u32 (lo = a, hi = b), RNE
__device__ __forceinline__ unsigned cvtpk(float a, float b) {
  unsigned r;
  asm("v_cvt_pk_bf16_f32 %0, %1, %2" : "=v"(r) : "v"(a), "v"(b));
  return r;
}
// v_permlane32_swap_b32: a.lanes[32:63] <-> b.lanes[0:31]
__device__ __forceinline__ void pswap(unsigned& a, unsigned& b) {
  asm("v_permlane32_swap_b32 %0, %1" : "+v"(a), "+v"(b));
}

// fragment read from a [rows][64] bf16 LDS tile with 16B-chunk XOR swizzle
__device__ __forceinline__ bf16x8 frag_ld(const unsigned short* base, int row, int kb, int hi) {
  const int byteoff = row * 128 + ((((kb << 1) + hi) ^ (row & 7)) << 4);
  return *(const bf16x8*)((const char*)base + byteoff);
}

// Fragment-ordered global layouts (consumed register-direct, coalesced):
//  f_f/g_f: [b][tile64(32)][slot(8)][row(64)][8 bf16]   (slot = k-chunk of c)
//  h_f:     [b][tile64(32)][slot(8)][c-row(256)][8 bf16] (slot = k-chunk of n)

// ---------------- Kernel 0a: pack weights -> bf16 swizzled Wall[384][256] ----
__global__ __launch_bounds__(256) void pack_kernel(
    const float* __restrict__ Wf, const float* __restrict__ bf,
    const float* __restrict__ Wg, const float* __restrict__ bg,
    const float* __restrict__ Wh, const float* __restrict__ bh,
    unsigned short* __restrict__ Wall, float* __restrict__ ball)
{
    const int t = threadIdx.x;
    const int o = blockIdx.x * 64 + (t >> 2);
    const int cq = (t & 3) * 64;
    const float* W; const float* bias; int r;
    if (o < 64)       { W = Wf; bias = bf; r = o; }
    else if (o < 128) { W = Wg; bias = bg; r = o - 64; }
    else              { W = Wh; bias = bh; r = o - 128; }
    for (int j = 0; j < 64; ++j) {
        const int c = cq + j;
        const int chunk = ((c >> 3) & 7) ^ (o & 7);
        Wall[(size_t)o * 256 + (c & ~63) + chunk * 8 + (c & 7)] = f2bf(W[(size_t)r * 256 + c]);
    }
    if ((t & 3) == 0) ball[o] = bias[r];
}

// ---------------- Kernel 1: projections via MFMA, fused x-transpose ----------
__global__ __launch_bounds__(256) void projmm_kernel(
    const unsigned short* __restrict__ Wall, const float* __restrict__ ball,
    const float* __restrict__ x,
    unsigned short* __restrict__ f_f, unsigned short* __restrict__ g_f,
    unsigned short* __restrict__ h_f)
{
    const int L = blockIdx.x;
    const int slot = L >> 3;
    const int b  = (L & 7) + (slot >= 48 ? 8 : 0);
    const int id2 = (slot >= 48) ? slot - 48 : slot;
    const int ot = id2 % 3, nt = id2 / 3;

    __shared__ __align__(16) unsigned short Sbuf[2][2][128 * 64];
    __shared__ float biasS[128];

    const int t = threadIdx.x, w = t >> 6, lane = t & 63, hi = lane >> 5, ln = lane & 31;
    const int oh = w & 1, nh = w >> 1;

    if (t < 128) biasS[t] = ball[ot * 128 + t];

    auto STAGE = [&](int k, int buf) {
        #pragma unroll
        for (int p = 0; p < 4; ++p) {
            const int q = p * 256 + t, r = q >> 3, cc = q & 7;
            gload16((const char*)Wall + ((size_t)(ot*128 + r) * 256 + k*64 + cc*8) * 2,
                    (char*)&Sbuf[buf][0][0] + q * 16);
        }
        const int row = t & 127;
        const int thi = t >> 7;
        const float* xsrc = x + ((size_t)b * C_ + k*64) * N_ + nt*128 + row;
        unsigned short* Xd = &Sbuf[buf][1][0];
        #pragma unroll
        for (int p = 0; p < 4; ++p) {
            const int k8 = p*2 + thi;
            u16x8 v;
            #pragma unroll
            for (int j = 0; j < 8; ++j)
                v[j] = f2bf(xsrc[(size_t)(k8*8 + j) * N_]);
            *(u16x8*)&Xd[(row * 8 + (k8 ^ (row & 7))) * 8] = v;
        }
    };

    f32x16 a00 = zero16(), a01 = zero16(), a10 = zero16(), a11 = zero16();

    STAGE(0, 0);
    for (int k = 0; k < 4; ++k) {
        __syncthreads();
        if (k < 3) STAGE(k + 1, (k + 1) & 1);
        const unsigned short* Wl = &Sbuf[k & 1][0][0];
        const unsigned short* Xl = &Sbuf[k & 1][1][0];
        #pragma unroll
        for (int kb = 0; kb < 4; ++kb) {
            bf16x8 w0 = frag_ld(Wl, oh*64 + ln,      kb, hi);
            bf16x8 w1 = frag_ld(Wl, oh*64 + 32 + ln, kb, hi);
            bf16x8 x0 = frag_ld(Xl, nh*64 + ln,      kb, hi);
            bf16x8 x1 = frag_ld(Xl, nh*64 + 32 + ln, kb, hi);
            a00 = __builtin_amdgcn_mfma_f32_32x32x16_bf16(w0, x0, a00, 0, 0, 0);
            a01 = __builtin_amdgcn_mfma_f32_32x32x16_bf16(w0, x1, a01, 0, 0, 0);
            a10 = __builtin_amdgcn_mfma_f32_32x32x16_bf16(w1, x0, a10, 0, 0, 0);
            a11 = __builtin_amdgcn_mfma_f32_32x32x16_bf16(w1, x1, a11, 0, 0, 0);
        }
    }

    if (ot == 0) {
        unsigned short* y = (oh == 0) ? f_f : g_f;
        const int tile64 = nt*2 + nh;
        #pragma unroll
        for (int j = 0; j < 2; ++j) {
            const int row = j*32 + ln;
            #pragma unroll
            for (int i = 0; i < 2; ++i) {
                const f32x16& a = (i == 0) ? (j == 0 ? a00 : a01)
                                           : (j == 0 ? a10 : a11);
                float v[16];
                #pragma unroll
                for (int r = 0; r < 16; ++r) {
                    const int cl = i*32 + (r & 3) + ((r >> 2) << 3) + 4*hi;
                    v[r] = fmaxf(a[r] + biasS[oh*64 + cl], 0.f);
                }
                #pragma unroll
                for (int kpa = 0; kpa < 2; ++kpa) {
                    unsigned u00 = cvtpk(v[8*kpa+0], v[8*kpa+1]);
                    unsigned u10 = cvtpk(v[8*kpa+2], v[8*kpa+3]);
                    unsigned u01 = cvtpk(v[8*kpa+4], v[8*kpa+5]);
                    unsigned u11 = cvtpk(v[8*kpa+6], v[8*kpa+7]);
                    pswap(u00, u01);
                    pswap(u10, u11);
                    union { unsigned u[4]; u16x8 w8; } pk;
                    pk.u[0] = u00; pk.u[1] = u10; pk.u[2] = u01; pk.u[3] = u11;
                    const int ch = i*4 + kpa*2 + hi;
                    *(u16x8*)&y[((((size_t)b*32 + tile64)*8 + ch)*64 + row) * 8] = pk.w8;
                }
            }
        }
    } else {
        __syncthreads();
        unsigned short* Ht = &Sbuf[0][0][0];   // 128 x 128 bf16 = 32KB
        #pragma unroll
        for (int j = 0; j < 2; ++j) {
            const int n_lo = nh*64 + j*32 + ln;
            const int chunk = n_lo >> 3;
            #pragma unroll
            for (int i = 0; i < 2; ++i) {
                const f32x16& a = (i == 0) ? (j == 0 ? a00 : a01)
                                           : (j == 0 ? a10 : a11);
                #pragma unroll
                for (int r = 0; r < 16; ++r) {
                    const int o_lo = oh*64 + i*32 + (r & 3) + ((r >> 2) << 3) + 4*hi;
                    const int chs = (chunk & 8) | ((chunk ^ o_lo) & 7);
                    Ht[o_lo * 128 + chs * 8 + (n_lo & 7)] =
                        f2bf(fmaxf(a[r] + biasS[o_lo], 0.f));
                }
            }
        }
        __syncthreads();
        const int o_l = t & 127, half = t >> 7;
        const int c = (ot - 1) * 128 + o_l;
        const size_t tbase = ((size_t)b*32 + nt*2 + half) * 8;
        #pragma unroll
        for (int c8 = 0; c8 < 8; ++c8) {
            const int chunk = half*8 + c8;
            const int chs = (chunk & 8) | ((chunk ^ o_l) & 7);
            *(u16x8*)&h_f[((tbase + c8)*256 + c) * 8] =
                *(const u16x8*)&Ht[o_l * 128 + chs * 8];
        }
    }
}

// ---------------- Kernel 2: row stats — coalesced frag-direct loads ----------
__global__ __launch_bounds__(256) void stats_kernel(
    const unsigned short* __restrict__ f_f, const unsigned short* __restrict__ g_f,
    float* __restrict__ LL2)
{
    const int L = blockIdx.x;
    const int slot = L >> 3;
    const int b  = (L & 7) + (slot >= 32 ? 8 : 0);
    const int nb64 = (slot >= 32) ? slot - 32 : slot;

    __shared__ float pM[2][64];
    __shared__ float pZ[2][64];

    const int t = threadIdx.x;
    const int w = t >> 6, lane = t & 63, hi = lane >> 5, ln = lane & 31;
    const int mb = w >> 1, nb2 = w & 1;

    bf16x8 gf[4];
    #pragma unroll
    for (int kc = 0; kc < 4; ++kc)
        gf[kc] = *(const bf16x8*)&g_f[((((size_t)b*32 + nb64)*8 + kc*2+hi)*64 + nb2*32+ln) * 8];

    auto loadF = [&](int s, bf16x8 (&F)[4]) {
        #pragma unroll
        for (int kc = 0; kc < 4; ++kc)
            F[kc] = *(const bf16x8*)&f_f[((((size_t)b*32 + s)*8 + kc*2+hi)*64 + mb*32+ln) * 8];
    };

    float runM = -1e30f, runZ = 0.f;
    constexpr int NS = N_ / 64;

    bf16x8 Fa[4], Fb[4];
    loadF(0, Fa);

    auto step = [&](int s, bf16x8 (&Fc)[4], bf16x8 (&Fn)[4]) {
        const int sn = (s + 1 < NS) ? s + 1 : NS - 1;
        loadF(sn, Fn);
        f32x16 sacc = zero16();
        #pragma unroll
        for (int kc = 0; kc < 4; ++kc)
            sacc = __builtin_amdgcn_mfma_f32_32x32x16_bf16(Fc[kc], gf[kc], sacc, 0, 0, 0);
        float lm = sacc[0];
        #pragma unroll
        for (int r = 1; r < 16; ++r) lm = fmaxf(lm, sacc[r]);
        const float nm = fmaxf(runM, lm);
        float ssum = 0.f;
        #pragma unroll
        for (int r = 0; r < 16; ++r) ssum += __expf(sacc[r] - nm);
        runZ = runZ * __expf(runM - nm) + ssum;
        runM = nm;
    };

    for (int s2 = 0; s2 < NS / 2; ++s2) {
        step(2 * s2,     Fa, Fb);
        step(2 * s2 + 1, Fb, Fa);
    }

    {
        const float oM = __shfl_xor(runM, 32);
        const float oZ = __shfl_xor(runZ, 32);
        const float Mf = fmaxf(runM, oM);
        const float Zf = runZ * __expf(runM - Mf) + oZ * __expf(oM - Mf);
        if (lane < 32) { pM[mb][nb2 * 32 + lane] = Mf; pZ[mb][nb2 * 32 + lane] = Zf; }
    }
    __syncthreads();
    if (t < 64) {
        const float m0 = pM[0][t], m1 = pM[1][t];
        const float M  = fmaxf(m0, m1);
        const float Z  = pZ[0][t] * __expf(m0 - M) + pZ[1][t] * __expf(m1 - M);
        LL2[(size_t)b * N_ + nb64 * 64 + t] = fmaf(M, kLOG2E, log2f(Z));
    }
}

// ---------------- Kernel 3: fused output — r13-best (57.5 us measured) ------
// 1 barrier/tile, dbuf H regs, frag-direct G/H/F; LDS = P dbuf 16K + LL 8K.
__global__ __launch_bounds__(256, 2) void out_kernel(
    const float* __restrict__ x,
    const unsigned short* __restrict__ f_f, const unsigned short* __restrict__ g_f,
    const unsigned short* __restrict__ h_f,
    const float* __restrict__ LL2,
    const float* __restrict__ gamma_p, float* __restrict__ out)
{
    const int L = blockIdx.x;                      // 512 blocks
    const int slot = L >> 3;                       // 0..63
    const int b = (L & 7) + (slot >= 32 ? 8 : 0);
    const int mb64 = (slot >= 32) ? slot - 32 : slot;
    const int mbase = mb64 * 64;

    __shared__ __align__(16) unsigned short P_lds[2][8 * 64 * 8];  // 16 KB
    __shared__ __align__(16) float LL_lds[N_];                     // 8 KB

    const int t = threadIdx.x;
    const int w = t >> 6, lane = t & 63, hi = lane >> 5, ln = lane & 31;
    const int mw = w & 1, nw = w >> 1;   // producer: 32m x 32n chunk
    const int cb = w;                    // consumer: 64 c rows
    constexpr int NT = N_ / 64;

    // f frags (B-operand of swapped S), coalesced, loaded once
    bf16x8 ff[4];
    #pragma unroll
    for (int kc = 0; kc < 4; ++kc)
        ff[kc] = *(const bf16x8*)&f_f[((((size_t)b*32 + mb64)*8 + kc*2+hi)*64 + mw*32+ln) * 8];

    bf16x8 Gf[4];
    auto LOAD_G = [&](int tt) {
        #pragma unroll
        for (int kc = 0; kc < 4; ++kc)
            Gf[kc] = *(const bf16x8*)&g_f[((((size_t)b*32 + tt)*8 + kc*2+hi)*64 + nw*32+ln) * 8];
    };
    auto LOAD_H = [&](int tt, bf16x8 (&H)[8]) {
        #pragma unroll
        for (int ci = 0; ci < 2; ++ci)
            #pragma unroll
            for (int kn = 0; kn < 4; ++kn)
                H[ci*4+kn] = *(const bf16x8*)&h_f[((((size_t)b*32 + tt)*8 + kn*2+hi)*256 +
                                                   cb*64 + ci*32 + ln) * 8];
    };

    // exp + pack sacc (S of tile ttn) -> P_lds[pbuf]
    auto EXPPACK = [&](f32x16& sacc, int ttn, int pbuf) {
        float4 llv[4];
        #pragma unroll
        for (int q = 0; q < 4; ++q)
            llv[q] = *(const float4*)&LL_lds[ttn*64 + nw*32 + q*8 + hi*4];
        #pragma unroll
        for (int r = 0; r < 16; ++r) {
            const float ll = ((const float*)&llv[r >> 2])[r & 3];
            sacc[r] = exp2f(fmaf(sacc[r], kLOG2E, -ll));
        }
        #pragma unroll
        for (int kpa = 0; kpa < 2; ++kpa) {
            unsigned u00 = cvtpk(sacc[8*kpa+0], sacc[8*kpa+1]);
            unsigned u10 = cvtpk(sacc[8*kpa+2], sacc[8*kpa+3]);
            unsigned u01 = cvtpk(sacc[8*kpa+4], sacc[8*kpa+5]);
            unsigned u11 = cvtpk(sacc[8*kpa+6], sacc[8*kpa+7]);
            pswap(u00, u01);
            pswap(u10, u11);
            union { unsigned u[4]; bf16x8 v; } pk;
            pk.u[0] = u00; pk.u[1] = u10; pk.u[2] = u01; pk.u[3] = u11;
            *(bf16x8*)((char*)&P_lds[pbuf][0] +
                ((4*nw + 2*kpa + hi) * 64 + mw*32 + ln) * 16) = pk.v;
        }
    };

    // ---- prologue
    {
        const char* lsrc = (const char*)(LL2 + (size_t)b * N_);
        gload16(lsrc + t * 16,        (char*)LL_lds + t * 16);
        gload16(lsrc + 4096 + t * 16, (char*)LL_lds + 4096 + t * 16);
    }
    __syncthreads();          // LL staged & visible
    LOAD_G(0);
    {   // P(0) -> P_lds[0]
        f32x16 s0 = zero16();
        #pragma unroll
        for (int kc = 0; kc < 4; ++kc)
            s0 = __builtin_amdgcn_mfma_f32_32x32x16_bf16(Gf[kc], ff[kc], s0, 0, 0, 0);
        EXPPACK(s0, 0, 0);
    }
    bf16x8 HA[8], HB[8];
    LOAD_H(0, HA);
    LOAD_G(1);
    LOAD_H(1, HB);

    f32x16 a00 = zero16(), a01 = zero16(), a10 = zero16(), a11 = zero16();

    auto body = [&](int tt, bf16x8 (&Hc)[8]) {
        __syncthreads();      // P[tt&1] visible block-wide (single barrier/iter)
        const int cur = tt & 1;

        __builtin_amdgcn_s_setprio(1);
        #pragma unroll
        for (int kb = 0; kb < 4; ++kb) {
            bf16x8 pb0 = *(const bf16x8*)((const char*)&P_lds[cur][0] +
                             (((kb << 1) + hi) * 64 + ln) * 16);
            bf16x8 pb1 = *(const bf16x8*)((const char*)&P_lds[cur][0] +
                             (((kb << 1) + hi) * 64 + 32 + ln) * 16);
            a00 = __builtin_amdgcn_mfma_f32_32x32x16_bf16(Hc[kb],   pb0, a00, 0, 0, 0);
            a01 = __builtin_amdgcn_mfma_f32_32x32x16_bf16(Hc[kb],   pb1, a01, 0, 0, 0);
            a10 = __builtin_amdgcn_mfma_f32_32x32x16_bf16(Hc[4+kb], pb0, a10, 0, 0, 0);
            a11 = __builtin_amdgcn_mfma_f32_32x32x16_bf16(Hc[4+kb], pb1, a11, 0, 0, 0);
        }
        __builtin_amdgcn_s_setprio(0);

        if (tt + 2 < NT) LOAD_H(tt + 2, Hc);   // refill just-consumed buffer

        if (tt + 1 < NT) {
            f32x16 sacc = zero16();            // S(tt+1): Gf loaded a full iter ago
            #pragma unroll
            for (int kc = 0; kc < 4; ++kc)
                sacc = __builtin_amdgcn_mfma_f32_32x32x16_bf16(Gf[kc], ff[kc], sacc, 0, 0, 0);
            if (tt + 2 < NT) LOAD_G(tt + 2);   // Gf free after S-MFMA issues
            EXPPACK(sacc, tt + 1, cur ^ 1);    // exp overlaps the G/H loads
        }
    };

    for (int t2 = 0; t2 < NT / 2; ++t2) {
        body(2 * t2,     HA);
        body(2 * t2 + 1, HB);
    }

    // ---- epilogue: out = gamma*o + x
    const float gamma = gamma_p[0];
    #pragma unroll
    for (int ci = 0; ci < 2; ++ci) {
        #pragma unroll
        for (int mi = 0; mi < 2; ++mi) {
            const f32x16& a = (ci == 0) ? (mi == 0 ? a00 : a01)
                                        : (mi == 0 ? a10 : a11);
            #pragma unroll
            for (int r = 0; r < 16; ++r) {
                const int c = cb * 64 + ci * 32 + (r & 3) + ((r >> 2) << 3) + (hi << 2);
                const int m = mbase + mi * 32 + ln;
                const size_t idx = ((size_t)b * C_ + c) * N_ + m;
                out[idx] = fmaf(gamma, a[r], x[idx]);
            }
        }
    }
}

extern "C" void kernel_launch(void* const* d_in, const int* in_sizes, int n_in,
                              void* d_out, int out_size, void* d_ws, size_t ws_size,
                              hipStream_t stream)
{
    (void)in_sizes; (void)n_in; (void)out_size; (void)ws_size;
    const float* x     = (const float*)d_in[0];
    const float* Wf    = (const float*)d_in[1];
    const float* bf    = (const float*)d_in[2];
    const float* Wg    = (const float*)d_in[3];
    const float* bg    = (const float*)d_in[4];
    const float* Wh    = (const float*)d_in[5];
    const float* bh    = (const float*)d_in[6];
    const float* gamma = (const float*)d_in[7];
    float* out = (float*)d_out;

    unsigned short* f_f  = (unsigned short*)d_ws;                 // [B][32][8][64][8] bf16
    unsigned short* g_f  = f_f + (size_t)B_ * N_ * CQ_;           // [B][32][8][64][8] bf16
    unsigned short* h_f  = g_f + (size_t)B_ * N_ * CQ_;           // [B][32][8][256][8] bf16
    float* LL2_ws = (float*)(h_f + (size_t)B_ * C_ * N_);         // [B][N]
    unsigned short* Wall = (unsigned short*)(LL2_ws + (size_t)B_ * N_); // [384][256] bf16 swz
    float* ball  = (float*)(Wall + (size_t)384 * 256);            // [384]

    pack_kernel<<<dim3(6), 256, 0, stream>>>(Wf, bf, Wg, bg, Wh, bh, Wall, ball);
    projmm_kernel<<<dim3(768), 256, 0, stream>>>(Wall, ball, x, f_f, g_f, h_f);
    stats_kernel<<<dim3(512), 256, 0, stream>>>(f_f, g_f, LL2_ws);
    out_kernel<<<dim3(512), 256, 0, stream>>>(x, f_f, g_f, h_f, LL2_ws, gamma, out);
}